// Round 1
// baseline (183.990 us; speedup 1.0000x reference)
//
#include <hip/hip_runtime.h>
#include <stdint.h>

typedef unsigned short u16;
typedef __attribute__((ext_vector_type(8))) short short8;
typedef __attribute__((ext_vector_type(4))) float f32x4;

#define MFMA16 __builtin_amdgcn_mfma_f32_16x16x32_bf16

// sizes
#define B_ 1024
#define N_ 64
#define OBS_ 128
#define H_ 256
#define A_ 16
#define NH_ 4
#define MTOT (B_ * N_)   // 65536

__device__ __forceinline__ u16 f2bf(float f) {
  union { float f; uint32_t u; } v; v.f = f;
  uint32_t r = v.u + 0x7FFFu + ((v.u >> 16) & 1u);
  return (u16)(r >> 16);
}

union U8 { short8 v; u16 u[8]; };

// ---------------------------------------------------------------------------
// C[M,256] = act(A[M,K] @ W[256,K]^T + bias)  -> bf16 out
// 128x128 tile, BK=64, 4 waves (2x2), 4x4 16x16x32 fragments per wave.
// ---------------------------------------------------------------------------
template<typename TA, int K, bool RELU>
__global__ __launch_bounds__(256) void gemm_bt(
    const TA* __restrict__ A, const float* __restrict__ W,
    const float* __restrict__ bias, u16* __restrict__ C) {
  __shared__ u16 As[128][72];   // +8 bf16 pad (16B) -> spreads banks
  __shared__ u16 Bs[128][72];
  const int tid  = threadIdx.x;
  const int lane = tid & 63;
  const int wid  = tid >> 6;
  const int wr   = wid >> 1, wc = wid & 1;
  const int m0   = blockIdx.x * 128;
  const int n0   = blockIdx.y * 128;

  f32x4 acc[4][4];
#pragma unroll
  for (int m = 0; m < 4; m++)
#pragma unroll
    for (int n = 0; n < 4; n++)
      acc[m][n] = (f32x4){0.f, 0.f, 0.f, 0.f};

  const int ro = lane & 15;
  const int kg = (lane >> 4) << 3;

  for (int k0 = 0; k0 < K; k0 += 64) {
#pragma unroll
    for (int it = 0; it < 4; ++it) {
      const int vv = tid + it * 256;
      const int r = vv >> 3, c = (vv & 7) << 3;
      if (sizeof(TA) == 4) {               // fp32 input: convert on the fly
        const float* s = (const float*)A + (size_t)(m0 + r) * K + k0 + c;
        U8 pk;
#pragma unroll
        for (int j = 0; j < 8; j++) pk.u[j] = f2bf(s[j]);
        *(short8*)&As[r][c] = pk.v;
      } else {                             // bf16 input
        *(short8*)&As[r][c] =
            *(const short8*)((const u16*)A + (size_t)(m0 + r) * K + k0 + c);
      }
      {                                    // weights always fp32
        const float* s = W + (size_t)(n0 + r) * K + k0 + c;
        U8 pk;
#pragma unroll
        for (int j = 0; j < 8; j++) pk.u[j] = f2bf(s[j]);
        *(short8*)&Bs[r][c] = pk.v;
      }
    }
    __syncthreads();
#pragma unroll
    for (int kk = 0; kk < 64; kk += 32) {
      short8 af[4], bfr[4];
#pragma unroll
      for (int m = 0; m < 4; m++)
        af[m] = *(const short8*)&As[wr * 64 + m * 16 + ro][kk + kg];
#pragma unroll
      for (int n = 0; n < 4; n++)
        bfr[n] = *(const short8*)&Bs[wc * 64 + n * 16 + ro][kk + kg];
#pragma unroll
      for (int m = 0; m < 4; m++)
#pragma unroll
        for (int n = 0; n < 4; n++)
          acc[m][n] = MFMA16(af[m], bfr[n], acc[m][n], 0, 0, 0);
    }
    __syncthreads();
  }

#pragma unroll
  for (int n = 0; n < 4; n++) {
    const int col = n0 + wc * 64 + n * 16 + ro;
    const float bb = bias[col];
#pragma unroll
    for (int m = 0; m < 4; m++) {
      const int r0 = m0 + wr * 64 + m * 16 + ((lane >> 4) << 2);
#pragma unroll
      for (int j = 0; j < 4; j++) {
        float val = acc[m][n][j] + bb;
        if (RELU) val = fmaxf(val, 0.f);
        C[(size_t)(r0 + j) * 256 + col] = f2bf(val);
      }
    }
  }
}

// ---------------------------------------------------------------------------
// attention per (b,h): S = QK^T/8, mask by adj, softmax, O = P@V.
// writes in-place over the q-buffer slice (block-local, safe).
// ---------------------------------------------------------------------------
__global__ __launch_bounds__(256) void attn_kernel(
    const u16* qb, const u16* __restrict__ kb, const u16* __restrict__ vb,
    const float* __restrict__ adj, u16* ob) {
  const int bh = blockIdx.x;
  const int b = bh >> 2, h = bh & 3;
  const int tid = threadIdx.x, lane = tid & 63, w = tid >> 6;
  __shared__ u16 QPs[64][72];   // Q, later reused for P (bf16)
  __shared__ u16 Ks[64][72];
  __shared__ u16 Vt[64][72];    // V transposed: Vt[d][k]
  __shared__ float Sf[64][66];  // scores fp32
  const size_t base = ((size_t)b * 64) * 256 + h * 64;

  // phase 1: load tiles
  for (int i = tid; i < 512; i += 256) {
    const int r = i >> 3, c = (i & 7) << 3;
    const size_t g = base + (size_t)r * 256 + c;
    *(short8*)&QPs[r][c] = *(const short8*)(qb + g);
    *(short8*)&Ks[r][c]  = *(const short8*)(kb + g);
    U8 vv; vv.v = *(const short8*)(vb + g);
#pragma unroll
    for (int j = 0; j < 8; j++) Vt[c + j][r] = vv.u[j];
  }
  __syncthreads();

  const int ro = lane & 15;
  const int kg = (lane >> 4) << 3;

  // phase 2: S = QK^T / 8  (wave w handles rows 16w..16w+15)
  {
    f32x4 s[4];
#pragma unroll
    for (int n = 0; n < 4; n++) s[n] = (f32x4){0.f, 0.f, 0.f, 0.f};
#pragma unroll
    for (int kk = 0; kk < 64; kk += 32) {
      short8 af = *(const short8*)&QPs[w * 16 + ro][kk + kg];
#pragma unroll
      for (int n = 0; n < 4; n++) {
        short8 bf_ = *(const short8*)&Ks[n * 16 + ro][kk + kg];
        s[n] = MFMA16(af, bf_, s[n], 0, 0, 0);
      }
    }
#pragma unroll
    for (int n = 0; n < 4; n++)
#pragma unroll
      for (int j = 0; j < 4; j++)
        Sf[w * 16 + ((lane >> 4) << 2) + j][n * 16 + ro] = s[n][j] * 0.125f;
  }
  __syncthreads();

  // phase 3: masked softmax, one row per 4-thread team; write P (bf16) over Q
  {
    const int qr = tid >> 2, sub = tid & 3;
    const float* arow = adj + ((size_t)b * 64 + qr) * 64;
    float sv[16], ev[16];
    float mx = -3.0e38f;
#pragma unroll
    for (int i = 0; i < 16; i++) {
      const int kk = sub + (i << 2);
      const float a = arow[kk];
      const float s = Sf[qr][kk];
      sv[i] = (a != 0.f) ? s : -3.0e38f;
      mx = fmaxf(mx, sv[i]);
    }
    mx = fmaxf(mx, __shfl_xor(mx, 1));
    mx = fmaxf(mx, __shfl_xor(mx, 2));
    float sum = 0.f;
#pragma unroll
    for (int i = 0; i < 16; i++) {
      const float e = (sv[i] > -1.0e37f) ? __expf(sv[i] - mx) : 0.f;
      ev[i] = e; sum += e;
    }
    sum += __shfl_xor(sum, 1);
    sum += __shfl_xor(sum, 2);
    const float inv = 1.0f / sum;
#pragma unroll
    for (int i = 0; i < 16; i++) QPs[qr][sub + (i << 2)] = f2bf(ev[i] * inv);
  }
  __syncthreads();

  // phase 4: O = P @ V  (Vt[d][k] gives contiguous b-frags)
  {
    f32x4 o[4];
#pragma unroll
    for (int n = 0; n < 4; n++) o[n] = (f32x4){0.f, 0.f, 0.f, 0.f};
#pragma unroll
    for (int kk = 0; kk < 64; kk += 32) {
      short8 pf = *(const short8*)&QPs[w * 16 + ro][kk + kg];
#pragma unroll
      for (int n = 0; n < 4; n++) {
        short8 vf = *(const short8*)&Vt[n * 16 + ro][kk + kg];
        o[n] = MFMA16(pf, vf, o[n], 0, 0, 0);
      }
    }
#pragma unroll
    for (int n = 0; n < 4; n++) {
      const int d = n * 16 + ro;
#pragma unroll
      for (int j = 0; j < 4; j++) {
        const int qr = w * 16 + ((lane >> 4) << 2) + j;
        ob[base + (size_t)qr * 256 + d] = f2bf(o[n][j]);
      }
    }
  }
}

// ---------------------------------------------------------------------------
// z[M,16] = attn[M,256] @ Wz[16,256]^T   (no bias, fp32 out)
// ---------------------------------------------------------------------------
__global__ __launch_bounds__(256) void zgemm(
    const u16* __restrict__ A, const u16* __restrict__ Wz,
    float* __restrict__ Z) {
  __shared__ u16 Ws[16][264];
  const int tid = threadIdx.x, lane = tid & 63, w = tid >> 6;
  for (int i = tid; i < 512; i += 256) {
    const int r = i >> 5, c = (i & 31) << 3;
    *(short8*)&Ws[r][c] = *(const short8*)(Wz + r * 256 + c);
  }
  __syncthreads();
  const int ro = lane & 15;
  const int kgb = (lane >> 4) << 3;
  f32x4 acc[2];
  acc[0] = (f32x4){0.f, 0.f, 0.f, 0.f};
  acc[1] = (f32x4){0.f, 0.f, 0.f, 0.f};
  const size_t abase = ((size_t)blockIdx.x * 128 + w * 32) * 256;
#pragma unroll
  for (int kk = 0; kk < 256; kk += 32) {
    short8 bf_ = *(const short8*)&Ws[ro][kk + kgb];
#pragma unroll
    for (int m = 0; m < 2; m++) {
      short8 af = *(const short8*)(A + abase + (size_t)(m * 16 + ro) * 256 + kk + kgb);
      acc[m] = MFMA16(af, bf_, acc[m], 0, 0, 0);
    }
  }
  const size_t zr = (size_t)blockIdx.x * 128 + w * 32;
#pragma unroll
  for (int m = 0; m < 2; m++)
#pragma unroll
    for (int j = 0; j < 4; j++)
      Z[(zr + m * 16 + ((lane >> 4) << 2) + j) * 16 + ro] = acc[m][j];
}

// ---------------------------------------------------------------------------
// out[b,n,a] = b3[a] + deg[n]*bz[a] + sum_m adj[b,n,m] * Z[b,m,a]
// ---------------------------------------------------------------------------
__global__ __launch_bounds__(256) void comm_kernel(
    const float* __restrict__ adj, const float* __restrict__ Z,
    const float* __restrict__ bz, const float* __restrict__ b3,
    float* __restrict__ out) {
  const int b = blockIdx.x, tid = threadIdx.x;
  __shared__ float adjs[64][65];
  __shared__ float zs[64][16];
  __shared__ float bzs[16], b3s[16];
  const float* ab = adj + (size_t)b * 4096;
  for (int i = tid; i < 4096; i += 256) adjs[i >> 6][i & 63] = ab[i];
  const float* zb = Z + (size_t)b * 1024;
  for (int i = tid; i < 1024; i += 256) zs[i >> 4][i & 15] = zb[i];
  if (tid < 16) { bzs[tid] = bz[tid]; b3s[tid] = b3[tid]; }
  __syncthreads();
  const int n = tid >> 2, a4 = (tid & 3) << 2;
  float a0 = 0.f, a1 = 0.f, a2 = 0.f, a3 = 0.f, deg = 0.f;
#pragma unroll
  for (int m = 0; m < 64; m++) {
    const float wv = adjs[n][m];
    deg += wv;
    a0 += wv * zs[m][a4 + 0];
    a1 += wv * zs[m][a4 + 1];
    a2 += wv * zs[m][a4 + 2];
    a3 += wv * zs[m][a4 + 3];
  }
  f32x4 r;
  r[0] = a0 + b3s[a4 + 0] + deg * bzs[a4 + 0];
  r[1] = a1 + b3s[a4 + 1] + deg * bzs[a4 + 1];
  r[2] = a2 + b3s[a4 + 2] + deg * bzs[a4 + 2];
  r[3] = a3 + b3s[a4 + 3] + deg * bzs[a4 + 3];
  *(f32x4*)(out + ((size_t)b * 64 + n) * 16 + a4) = r;
}

// ---------------------------------------------------------------------------
// prep1: M1 = Wc @ Wo (fp32), bv = bc + Wc @ bo
// ---------------------------------------------------------------------------
__global__ __launch_bounds__(256) void prep1(
    const float* __restrict__ Wc, const float* __restrict__ Wo,
    const float* __restrict__ bo, const float* __restrict__ bc,
    float* __restrict__ M1, float* __restrict__ bv) {
  const int j = blockIdx.x, d = threadIdx.x;
  __shared__ float wcr[256];
  __shared__ float red[4];
  wcr[d] = Wc[j * 256 + d];
  __syncthreads();
  float acc = 0.f;
  for (int i = 0; i < 256; i++) acc += wcr[i] * Wo[i * 256 + d];
  M1[j * 256 + d] = acc;
  float p = wcr[d] * bo[d];
  for (int off = 32; off >= 1; off >>= 1) p += __shfl_xor(p, off);
  if ((d & 63) == 0) red[d >> 6] = p;
  __syncthreads();
  if (d == 0) bv[j] = bc[j] + red[0] + red[1] + red[2] + red[3];
}

// ---------------------------------------------------------------------------
// prep2: Wz = W3 @ M1 (bf16), bz = W3 @ bv
// ---------------------------------------------------------------------------
__global__ __launch_bounds__(256) void prep2(
    const float* __restrict__ W3, const float* __restrict__ M1,
    const float* __restrict__ bv, u16* __restrict__ Wz,
    float* __restrict__ bz) {
  const int a = blockIdx.x, d = threadIdx.x;
  __shared__ float w3r[256];
  __shared__ float red[4];
  w3r[d] = W3[a * 256 + d];
  __syncthreads();
  float acc = 0.f;
  for (int j = 0; j < 256; j++) acc += w3r[j] * M1[j * 256 + d];
  Wz[a * 256 + d] = f2bf(acc);
  float p = w3r[d] * bv[d];
  for (int off = 32; off >= 1; off >>= 1) p += __shfl_xor(p, off);
  if ((d & 63) == 0) red[d >> 6] = p;
  __syncthreads();
  if (d == 0) bz[a] = red[0] + red[1] + red[2] + red[3];
}

// ---------------------------------------------------------------------------
extern "C" void kernel_launch(void* const* d_in, const int* in_sizes, int n_in,
                              void* d_out, int out_size, void* d_ws, size_t ws_size,
                              hipStream_t stream) {
  const float* obs = (const float*)d_in[0];
  const float* adj = (const float*)d_in[1];
  const float* W1  = (const float*)d_in[2];
  const float* b1  = (const float*)d_in[3];
  const float* W2  = (const float*)d_in[4];
  const float* b2  = (const float*)d_in[5];
  const float* Wq  = (const float*)d_in[6];
  const float* bq  = (const float*)d_in[7];
  const float* Wk  = (const float*)d_in[8];
  const float* bk  = (const float*)d_in[9];
  const float* Wv  = (const float*)d_in[10];
  const float* bvw = (const float*)d_in[11];
  const float* Wo  = (const float*)d_in[12];
  const float* bo  = (const float*)d_in[13];
  const float* Wc  = (const float*)d_in[14];
  const float* bc  = (const float*)d_in[15];
  const float* W3  = (const float*)d_in[16];
  const float* b3  = (const float*)d_in[17];
  float* out = (float*)d_out;

  char* ws = (char*)d_ws;
  const size_t BIG = (size_t)MTOT * 256 * 2;           // 33.5 MB per bf16 buffer
  u16* bufA = (u16*)(ws);                              // x1 -> q -> attn_out
  u16* bufB = (u16*)(ws + BIG);                        // x2
  u16* bufC = (u16*)(ws + 2 * BIG);                    // k
  u16* bufD = (u16*)(ws + 3 * BIG);                    // v
  float* Z  = (float*)(ws + 4 * BIG);                  // 4 MB
  float* M1 = (float*)(ws + 4 * BIG + (size_t)MTOT * 16 * 4);
  u16* Wz   = (u16*)((char*)M1 + 256 * 256 * 4);
  float* bv = (float*)((char*)Wz + 16 * 256 * 2);
  float* bz = (float*)((char*)bv + 1024);

  dim3 blk(256);
  prep1<<<dim3(256), blk, 0, stream>>>(Wc, Wo, bo, bc, M1, bv);
  prep2<<<dim3(16), blk, 0, stream>>>(W3, M1, bv, Wz, bz);

  gemm_bt<float, 128, true ><<<dim3(512, 2), blk, 0, stream>>>(obs,  W1, b1,  bufA);
  gemm_bt<u16,   256, true ><<<dim3(512, 2), blk, 0, stream>>>(bufA, W2, b2,  bufB);
  gemm_bt<u16,   256, false><<<dim3(512, 2), blk, 0, stream>>>(bufB, Wq, bq,  bufA);
  gemm_bt<u16,   256, false><<<dim3(512, 2), blk, 0, stream>>>(bufB, Wk, bk,  bufC);
  gemm_bt<u16,   256, false><<<dim3(512, 2), blk, 0, stream>>>(bufB, Wv, bvw, bufD);

  attn_kernel<<<dim3(4096), blk, 0, stream>>>(bufA, bufC, bufD, adj, bufA);
  zgemm<<<dim3(512), blk, 0, stream>>>(bufA, Wz, Z);
  comm_kernel<<<dim3(1024), blk, 0, stream>>>(adj, Z, bz, b3, out);
}